// Round 5
// baseline (681.432 us; speedup 1.0000x reference)
//
#include <hip/hip_runtime.h>
#include <hip/hip_bf16.h>

#define HD 128
#define ED 16
#define TD 32

typedef __attribute__((ext_vector_type(8))) short short8;
typedef __attribute__((ext_vector_type(4))) float float4v;

__device__ __forceinline__ float siluf(float v){ return v * (1.0f / (1.0f + __expf(-v))); }

// bf16 pack/unpack helpers (RTNE)
__device__ __forceinline__ unsigned int bfbits(float x){
  unsigned int a = __float_as_uint(x);
  return (a + 0x7fffu + ((a >> 16) & 1u)) >> 16;
}
__device__ __forceinline__ unsigned int packbf(float lo, float hi){
  return (bfbits(lo) & 0xffffu) | (bfbits(hi) << 16);
}
__device__ __forceinline__ float unplo(unsigned int w){ return __uint_as_float(w << 16); }
__device__ __forceinline__ float unphi(unsigned int w){ return __uint_as_float(w & 0xffff0000u); }
__device__ __forceinline__ float b2f(unsigned short s){ return __uint_as_float(((unsigned int)s) << 16); }
__device__ __forceinline__ unsigned short f2b(float x){ return (unsigned short)bfbits(x); }

__device__ __forceinline__ void unp8(uint4 u, float* f){
  f[0]=unplo(u.x); f[1]=unphi(u.x); f[2]=unplo(u.y); f[3]=unphi(u.y);
  f[4]=unplo(u.z); f[5]=unphi(u.z); f[6]=unplo(u.w); f[7]=unphi(u.w);
}

__device__ __forceinline__ void atomAddF(float* p, float v){
  unsafeAtomicAdd(p, v);  // HW global_atomic_add_f32 on gfx950
}

// ---------------------------------------------------------------------------
// Kernel 1: node-side first-layer GEMMs via MFMA (unchanged R4).
// ---------------------------------------------------------------------------
__global__ void __launch_bounds__(256) k_pre2(
    const float* __restrict__ h, const float* __restrict__ t_emb,
    const float* __restrict__ We_w1, const float* __restrict__ We_b1,
    const float* __restrict__ Wx_w1, const float* __restrict__ Wx_b1,
    const float* __restrict__ Wh_w1, const float* __restrict__ Wh_b1,
    unsigned short* __restrict__ Aes, unsigned short* __restrict__ Aed,
    unsigned short* __restrict__ Axs, unsigned short* __restrict__ Axd,
    unsigned short* __restrict__ zpre, int N)
{
  __shared__ unsigned short Wt[128 * 168];
  __shared__ unsigned short OutS[64 * 136];

  const int group = blockIdx.y;
  const float* Wsrc = (group <= 1) ? We_w1 : (group <= 3) ? Wx_w1 : Wh_w1;
  const float* bias = (group == 0) ? We_b1 : (group == 2) ? Wx_b1
                    : (group == 4) ? Wh_b1 : nullptr;
  unsigned short* out = (group == 0) ? Aes : (group == 1) ? Aed
                      : (group == 2) ? Axs : (group == 3) ? Axd : zpre;
  const int rowBase = (group == 1 || group == 3) ? 128 : 0;
  const int tBase   = (group == 0) ? 273 : (group == 2) ? 272 : -1;

  for (int i = threadIdx.x; i < 160 * 128; i += 256){
    int k = i >> 7, col = i & 127;
    float wv = 0.f;
    if (k < 128)      wv = Wsrc[(rowBase + k) * 128 + col];
    else if (tBase >= 0) wv = Wsrc[(tBase + (k - 128)) * 128 + col];
    Wt[col * 168 + k] = f2b(wv);
  }
  __syncthreads();

  const int lane = threadIdx.x & 63, w = threadIdx.x >> 6;
  const int m = lane & 15, q = lane >> 4;
  float bb[8];
  #pragma unroll
  for (int t = 0; t < 8; ++t) bb[t] = bias ? bias[t * 16 + m] : 0.f;

  const int ntiles = (N + 63) >> 6;
  for (int tile = blockIdx.x; tile < ntiles; tile += gridDim.x){
    const int n0 = tile << 6;
    const int n = min(n0 + w * 16 + m, N - 1);

    short8 a[5];
    #pragma unroll
    for (int step = 0; step < 4; ++step){
      float4 v0 = *(const float4*)(h + (size_t)n * 128 + step * 32 + q * 8);
      float4 v1 = *(const float4*)(h + (size_t)n * 128 + step * 32 + q * 8 + 4);
      union { short8 s; unsigned int u[4]; } av;
      av.u[0] = packbf(v0.x, v0.y); av.u[1] = packbf(v0.z, v0.w);
      av.u[2] = packbf(v1.x, v1.y); av.u[3] = packbf(v1.z, v1.w);
      a[step] = av.s;
    }
    {
      float4 v0 = *(const float4*)(t_emb + (size_t)n * 32 + q * 8);
      float4 v1 = *(const float4*)(t_emb + (size_t)n * 32 + q * 8 + 4);
      union { short8 s; unsigned int u[4]; } av;
      av.u[0] = packbf(v0.x, v0.y); av.u[1] = packbf(v0.z, v0.w);
      av.u[2] = packbf(v1.x, v1.y); av.u[3] = packbf(v1.z, v1.w);
      a[4] = av.s;
    }

    float4v acc[8];
    #pragma unroll
    for (int t = 0; t < 8; ++t) acc[t] = (float4v){0.f, 0.f, 0.f, 0.f};
    #pragma unroll
    for (int step = 0; step < 5; ++step){
      #pragma unroll
      for (int t = 0; t < 8; ++t){
        short8 b = *(const short8*)(Wt + (size_t)(t * 16 + m) * 168 + step * 32 + q * 8);
        acc[t] = __builtin_amdgcn_mfma_f32_16x16x32_bf16(a[step], b, acc[t], 0, 0, 0);
      }
    }

    #pragma unroll
    for (int t = 0; t < 8; ++t)
      #pragma unroll
      for (int r = 0; r < 4; ++r)
        OutS[(w * 16 + q * 4 + r) * 136 + t * 16 + m] = f2b(acc[t][r] + bb[t]);
    __syncthreads();
    for (int i = threadIdx.x; i < 64 * 16; i += 256){
      int node = i >> 4, seg = i & 15;
      int nn = n0 + node;
      if (nn < N)
        *(uint4*)(out + (size_t)nn * 128 + seg * 8) =
            *(const uint4*)(OutS + node * 136 + seg * 8);
    }
    __syncthreads();
  }
}

// ---------------------------------------------------------------------------
// Kernel 2: message path, wave-autonomous. One wave = one 16-edge tile,
// all 128 cols. No __syncthreads in the main loop.
// ---------------------------------------------------------------------------
__global__ void __launch_bounds__(256, 3) k_edge_msg(
    const int* __restrict__ ei, const float* __restrict__ x,
    const float* __restrict__ ea,
    const unsigned short* __restrict__ Aes, const unsigned short* __restrict__ Aed,
    const float* __restrict__ We_w1, const float* __restrict__ We_w2,
    const float* __restrict__ We_b2, const float* __restrict__ Watt_w,
    const float* __restrict__ Watt_b,
    float* __restrict__ msg_agg, int E)
{
  __shared__ unsigned short W2t[128 * 136];    // 34816 B, [col][k]
  __shared__ unsigned short Ssh[4][16 * 136];  // per-wave: sums -> u -> m (bf16)
  __shared__ float          distS[4][16];
  __shared__ int            dsh[4][16];

  const int tid = threadIdx.x;
  for (int i = tid; i < 128 * 128; i += 256){
    int col = i & 127, k = i >> 7;
    W2t[col * 136 + k] = f2b(We_w2[k * 128 + col]);
  }
  __syncthreads();

  const int lane = tid & 63, w = tid >> 6;
  const int m = lane & 15, q = lane >> 4;

  // register B-frags for the ea|dist tail (rows 257..272 = ea, 256 = dist)
  short8 Bt[8];
  float web2[8], watt[8];
  #pragma unroll
  for (int t = 0; t < 8; ++t){
    const int col = t * 16 + m;
    web2[t] = We_b2[col];
    watt[t] = Watt_w[col];
    union { short8 v; unsigned short u[8]; } bt;
    #pragma unroll
    for (int j = 0; j < 8; ++j){
      int k = q * 8 + j;
      float wv = (k < 16) ? We_w1[(257 + k) * 128 + col]
               : (k == 16 ? We_w1[256 * 128 + col] : 0.f);
      bt.u[j] = f2b(wv);
    }
    Bt[t] = bt.v;
  }
  const float attb = Watt_b[0];

  unsigned short* S = Ssh[w];
  float* dS = distS[w];
  int*   dI = dsh[w];

  const int tiles = (E + 15) >> 4;
  const int wid = blockIdx.x * 4 + w;
  const int nwv = gridDim.x * 4;

  for (int tb = wid; tb < tiles; tb += nwv){
    const int e0 = tb << 4;

    // per-edge scalars (lanes 0..15)
    if (lane < 16){
      int eC = min(e0 + lane, E - 1);
      int s = ei[eC], d = ei[E + eC];
      float dx = x[s * 3 + 0] - x[d * 3 + 0];
      float dy = x[s * 3 + 1] - x[d * 3 + 1];
      float dz = x[s * 3 + 2] - x[d * 3 + 2];
      dS[lane] = dx * dx + dy * dy + dz * dz;
      dI[lane] = d;
    }

    // table-sum staging: 16 adjacent lanes cover one 256B row (proven pattern)
    #pragma unroll
    for (int it = 0; it < 4; ++it){
      const int eg = q + 4 * it;
      const int eC = min(e0 + eg, E - 1);
      const int s = ei[eC], d = ei[E + eC];
      uint4 gs = *(const uint4*)(Aes + (size_t)s * HD + m * 8);
      uint4 gd = *(const uint4*)(Aed + (size_t)d * HD + m * 8);
      float fa[8], fb[8];
      unp8(gs, fa); unp8(gd, fb);
      union { short8 v; unsigned int u[4]; } sv;
      #pragma unroll
      for (int jj = 0; jj < 4; ++jj)
        sv.u[jj] = packbf(fa[2 * jj] + fb[2 * jj], fa[2 * jj + 1] + fb[2 * jj + 1]);
      *(short8*)(S + eg * 136 + m * 8) = sv.v;
    }

    // tail A-frag in regs: k<16 = ea (consecutive rows -> coalesced), k==16 = dist
    union { short8 v; unsigned int u[4]; } at;
    at.u[0] = at.u[1] = at.u[2] = at.u[3] = 0u;
    {
      const int eC2 = min(e0 + m, E - 1);
      if (q < 2){
        float4 v0 = *(const float4*)(ea + (size_t)eC2 * ED + q * 8);
        float4 v1 = *(const float4*)(ea + (size_t)eC2 * ED + q * 8 + 4);
        at.u[0] = packbf(v0.x, v0.y); at.u[1] = packbf(v0.z, v0.w);
        at.u[2] = packbf(v1.x, v1.y); at.u[3] = packbf(v1.z, v1.w);
      } else if (q == 2){
        at.u[0] = bfbits(dS[m]) & 0xffffu;
      }
    }

    // tail MFMA with C initialized from staged sums; then silu -> u (bf16)
    #pragma unroll
    for (int t = 0; t < 8; ++t){
      float4v ci;
      #pragma unroll
      for (int r = 0; r < 4; ++r)
        ci[r] = b2f(S[(q * 4 + r) * 136 + t * 16 + m]);
      float4v o = __builtin_amdgcn_mfma_f32_16x16x32_bf16(at.v, Bt[t], ci, 0, 0, 0);
      #pragma unroll
      for (int r = 0; r < 4; ++r)
        S[(q * 4 + r) * 136 + t * 16 + m] = f2b(siluf(o[r]));
    }

    // layer-2 MFMA, B from shared W2t
    float4v c2[8];
    #pragma unroll
    for (int t = 0; t < 8; ++t) c2[t] = (float4v){0.f, 0.f, 0.f, 0.f};
    #pragma unroll
    for (int step = 0; step < 4; ++step){
      short8 a2 = *(const short8*)(S + m * 136 + step * 32 + q * 8);
      #pragma unroll
      for (int t = 0; t < 8; ++t){
        short8 b = *(const short8*)(W2t + (size_t)(t * 16 + m) * 136 + step * 32 + q * 8);
        c2[t] = __builtin_amdgcn_mfma_f32_16x16x32_bf16(a2, b, c2[t], 0, 0, 0);
      }
    }

    // attention + write gated m-values (bf16) back into S
    #pragma unroll
    for (int r = 0; r < 4; ++r){
      float mp[8], p = 0.f;
      #pragma unroll
      for (int t = 0; t < 8; ++t){
        mp[t] = c2[t][r] + web2[t];
        p = fmaf(mp[t], watt[t], p);
      }
      p += __shfl_xor(p, 1); p += __shfl_xor(p, 2);
      p += __shfl_xor(p, 4); p += __shfl_xor(p, 8);
      float att = 1.f / (1.f + __expf(-(p + attb)));
      #pragma unroll
      for (int t = 0; t < 8; ++t)
        S[(q * 4 + r) * 136 + t * 16 + m] = f2b(att * mp[t]);
    }

    // atomic scatter: full 256B-contiguous per instruction (no write amp)
    #pragma unroll
    for (int i = 0; i < 32; ++i){
      const int eg = i >> 1, half = i & 1;
      if (e0 + eg < E){
        float v = b2f(S[eg * 136 + half * 64 + lane]);
        atomAddF(msg_agg + (size_t)dI[eg] * HD + half * 64 + lane, v);
      }
    }
  }
}

// ---------------------------------------------------------------------------
// Kernel 3: coord path, wave-autonomous (same structure).
// ---------------------------------------------------------------------------
__global__ void __launch_bounds__(256, 3) k_edge_coord(
    const int* __restrict__ ei, const float* __restrict__ x,
    const float* __restrict__ ea,
    const unsigned short* __restrict__ Axs, const unsigned short* __restrict__ Axd,
    const float* __restrict__ Wx_w1, const float* __restrict__ Wx_w2,
    const float* __restrict__ Wx_b2, const float* __restrict__ Wx_w3,
    float* __restrict__ xout, int E)
{
  __shared__ unsigned short W2t[128 * 136];    // 34816 B
  __shared__ unsigned short Ssh[4][16 * 136];
  __shared__ float          xaux[4][16 * 4];   // dx,dy,dz,rs per edge
  __shared__ int            dsh[4][16];

  const int tid = threadIdx.x;
  for (int i = tid; i < 128 * 128; i += 256){
    int col = i & 127, k = i >> 7;
    W2t[col * 136 + k] = f2b(Wx_w2[k * 128 + col]);
  }
  __syncthreads();

  const int lane = tid & 63, w = tid >> 6;
  const int m = lane & 15, q = lane >> 4;

  short8 Bt[8];
  float wxb2[8], w3v[8];
  #pragma unroll
  for (int t = 0; t < 8; ++t){
    const int col = t * 16 + m;
    wxb2[t] = Wx_b2[col];
    w3v[t]  = Wx_w3[col];
    union { short8 v; unsigned short u[8]; } bt;
    #pragma unroll
    for (int j = 0; j < 8; ++j){
      int k = q * 8 + j;
      bt.u[j] = f2b(k < 16 ? Wx_w1[(256 + k) * 128 + col] : 0.f);
    }
    Bt[t] = bt.v;
  }

  unsigned short* S = Ssh[w];
  float* xa = xaux[w];
  int*   dI = dsh[w];

  const int tiles = (E + 15) >> 4;
  const int wid = blockIdx.x * 4 + w;
  const int nwv = gridDim.x * 4;

  for (int tb = wid; tb < tiles; tb += nwv){
    const int e0 = tb << 4;

    if (lane < 16){
      int eC = min(e0 + lane, E - 1);
      int s = ei[eC], d = ei[E + eC];
      float dx = x[s * 3 + 0] - x[d * 3 + 0];
      float dy = x[s * 3 + 1] - x[d * 3 + 1];
      float dz = x[s * 3 + 2] - x[d * 3 + 2];
      float dist = dx * dx + dy * dy + dz * dz;
      xa[lane * 4 + 0] = dx;
      xa[lane * 4 + 1] = dy;
      xa[lane * 4 + 2] = dz;
      xa[lane * 4 + 3] = 2.5f / (sqrtf(dist + 1e-8f) + 1.0f);
      dI[lane] = d;
    }

    #pragma unroll
    for (int it = 0; it < 4; ++it){
      const int eg = q + 4 * it;
      const int eC = min(e0 + eg, E - 1);
      const int s = ei[eC], d = ei[E + eC];
      uint4 gs = *(const uint4*)(Axs + (size_t)s * HD + m * 8);
      uint4 gd = *(const uint4*)(Axd + (size_t)d * HD + m * 8);
      float fa[8], fb[8];
      unp8(gs, fa); unp8(gd, fb);
      union { short8 v; unsigned int u[4]; } sv;
      #pragma unroll
      for (int jj = 0; jj < 4; ++jj)
        sv.u[jj] = packbf(fa[2 * jj] + fb[2 * jj], fa[2 * jj + 1] + fb[2 * jj + 1]);
      *(short8*)(S + eg * 136 + m * 8) = sv.v;
    }

    union { short8 v; unsigned int u[4]; } at;
    at.u[0] = at.u[1] = at.u[2] = at.u[3] = 0u;
    if (q < 2){
      const int eC2 = min(e0 + m, E - 1);
      float4 v0 = *(const float4*)(ea + (size_t)eC2 * ED + q * 8);
      float4 v1 = *(const float4*)(ea + (size_t)eC2 * ED + q * 8 + 4);
      at.u[0] = packbf(v0.x, v0.y); at.u[1] = packbf(v0.z, v0.w);
      at.u[2] = packbf(v1.x, v1.y); at.u[3] = packbf(v1.z, v1.w);
    }

    #pragma unroll
    for (int t = 0; t < 8; ++t){
      float4v ci;
      #pragma unroll
      for (int r = 0; r < 4; ++r)
        ci[r] = b2f(S[(q * 4 + r) * 136 + t * 16 + m]);
      float4v o = __builtin_amdgcn_mfma_f32_16x16x32_bf16(at.v, Bt[t], ci, 0, 0, 0);
      #pragma unroll
      for (int r = 0; r < 4; ++r)
        S[(q * 4 + r) * 136 + t * 16 + m] = f2b(siluf(o[r]));
    }

    float4v c2[8];
    #pragma unroll
    for (int t = 0; t < 8; ++t) c2[t] = (float4v){0.f, 0.f, 0.f, 0.f};
    #pragma unroll
    for (int step = 0; step < 4; ++step){
      short8 a2 = *(const short8*)(S + m * 136 + step * 32 + q * 8);
      #pragma unroll
      for (int t = 0; t < 8; ++t){
        short8 b = *(const short8*)(W2t + (size_t)(t * 16 + m) * 136 + step * 32 + q * 8);
        c2[t] = __builtin_amdgcn_mfma_f32_16x16x32_bf16(a2, b, c2[t], 0, 0, 0);
      }
    }

    // coord weight + scatter (3 atomics per edge)
    #pragma unroll
    for (int r = 0; r < 4; ++r){
      float p = 0.f;
      #pragma unroll
      for (int t = 0; t < 8; ++t)
        p = fmaf(siluf(c2[t][r] + wxb2[t]), w3v[t], p);
      p += __shfl_xor(p, 1); p += __shfl_xor(p, 2);
      p += __shfl_xor(p, 4); p += __shfl_xor(p, 8);
      const int eg = q * 4 + r;
      float sc = tanhf(p) * xa[eg * 4 + 3];
      if (m < 3 && e0 + eg < E)
        atomAddF(xout + (size_t)dI[eg] * 3 + m, xa[eg * 4 + m] * sc);
    }
  }
}

// ---------------------------------------------------------------------------
// Kernel 4: z2 = bf16( silu( zpre + msg @ Wh_w1[128:256] ) )  (unchanged R4)
// ---------------------------------------------------------------------------
__global__ void __launch_bounds__(256) k_h1b2(
    const float* __restrict__ msg, const unsigned short* __restrict__ zpre,
    const float* __restrict__ Wh_w1, unsigned short* __restrict__ z2, int N)
{
  __shared__ unsigned short Wt[128 * 136];
  __shared__ unsigned short OutS[64 * 136];

  for (int i = threadIdx.x; i < 128 * 128; i += 256){
    int k = i >> 7, col = i & 127;
    Wt[col * 136 + k] = f2b(Wh_w1[(128 + k) * 128 + col]);
  }
  __syncthreads();

  const int lane = threadIdx.x & 63, w = threadIdx.x >> 6;
  const int m = lane & 15, q = lane >> 4;

  const int ntiles = (N + 63) >> 6;
  for (int tile = blockIdx.x; tile < ntiles; tile += gridDim.x){
    const int n0 = tile << 6;
    const int n = min(n0 + w * 16 + m, N - 1);

    short8 a[4];
    #pragma unroll
    for (int step = 0; step < 4; ++step){
      float4 v0 = *(const float4*)(msg + (size_t)n * 128 + step * 32 + q * 8);
      float4 v1 = *(const float4*)(msg + (size_t)n * 128 + step * 32 + q * 8 + 4);
      union { short8 s; unsigned int u[4]; } av;
      av.u[0] = packbf(v0.x, v0.y); av.u[1] = packbf(v0.z, v0.w);
      av.u[2] = packbf(v1.x, v1.y); av.u[3] = packbf(v1.z, v1.w);
      a[step] = av.s;
    }

    float4v acc[8];
    #pragma unroll
    for (int t = 0; t < 8; ++t) acc[t] = (float4v){0.f, 0.f, 0.f, 0.f};
    #pragma unroll
    for (int step = 0; step < 4; ++step){
      #pragma unroll
      for (int t = 0; t < 8; ++t){
        short8 b = *(const short8*)(Wt + (size_t)(t * 16 + m) * 136 + step * 32 + q * 8);
        acc[t] = __builtin_amdgcn_mfma_f32_16x16x32_bf16(a[step], b, acc[t], 0, 0, 0);
      }
    }

    #pragma unroll
    for (int t = 0; t < 8; ++t)
      #pragma unroll
      for (int r = 0; r < 4; ++r)
        OutS[(w * 16 + q * 4 + r) * 136 + t * 16 + m] = f2b(acc[t][r]);
    __syncthreads();
    for (int i = threadIdx.x; i < 64 * 16; i += 256){
      int node = i >> 4, seg = i & 15;
      int nn = n0 + node;
      if (nn < N){
        uint4 dv = *(const uint4*)(OutS + node * 136 + seg * 8);
        uint4 zv = *(const uint4*)(zpre + (size_t)nn * 128 + seg * 8);
        float fd[8], fz[8];
        unp8(dv, fd); unp8(zv, fz);
        uint4 ov;
        ov.x = packbf(siluf(fz[0] + fd[0]), siluf(fz[1] + fd[1]));
        ov.y = packbf(siluf(fz[2] + fd[2]), siluf(fz[3] + fd[3]));
        ov.z = packbf(siluf(fz[4] + fd[4]), siluf(fz[5] + fd[5]));
        ov.w = packbf(siluf(fz[6] + fd[6]), siluf(fz[7] + fd[7]));
        *(uint4*)(z2 + (size_t)nn * 128 + seg * 8) = ov;
      }
    }
    __syncthreads();
  }
}

// ---------------------------------------------------------------------------
// Kernel 5: hout = h + z2 @ Wh_w2 + Wh_b2  (unchanged R4)
// ---------------------------------------------------------------------------
__global__ void __launch_bounds__(256) k_h22(
    const float* __restrict__ h, const unsigned short* __restrict__ z2,
    const float* __restrict__ Wh_w2, const float* __restrict__ Wh_b2,
    float* __restrict__ hout, int N)
{
  __shared__ unsigned short Wt[128 * 136];
  __shared__ float OutSf[64 * 132];

  for (int i = threadIdx.x; i < 128 * 128; i += 256){
    int k = i >> 7, col = i & 127;
    Wt[col * 136 + k] = f2b(Wh_w2[k * 128 + col]);
  }
  __syncthreads();

  const int lane = threadIdx.x & 63, w = threadIdx.x >> 6;
  const int m = lane & 15, q = lane >> 4;
  float bb[8];
  #pragma unroll
  for (int t = 0; t < 8; ++t) bb[t] = Wh_b2[t * 16 + m];

  const int ntiles = (N + 63) >> 6;
  for (int tile = blockIdx.x; tile < ntiles; tile += gridDim.x){
    const int n0 = tile << 6;
    const int n = min(n0 + w * 16 + m, N - 1);

    short8 a[4];
    #pragma unroll
    for (int step = 0; step < 4; ++step)
      a[step] = *(const short8*)(z2 + (size_t)n * 128 + step * 32 + q * 8);

    float4v acc[8];
    #pragma unroll
    for (int t = 0; t < 8; ++t) acc[t] = (float4v){0.f, 0.f, 0.f, 0.f};
    #pragma unroll
    for (int step = 0; step < 4; ++step){
      #pragma unroll
      for (int t = 0; t < 8; ++t){
        short8 b = *(const short8*)(Wt + (size_t)(t * 16 + m) * 136 + step * 32 + q * 8);
        acc[t] = __builtin_amdgcn_mfma_f32_16x16x32_bf16(a[step], b, acc[t], 0, 0, 0);
      }
    }

    #pragma unroll
    for (int t = 0; t < 8; ++t)
      #pragma unroll
      for (int r = 0; r < 4; ++r)
        OutSf[(w * 16 + q * 4 + r) * 132 + t * 16 + m] = acc[t][r] + bb[t];
    __syncthreads();
    for (int i = threadIdx.x; i < 64 * 32; i += 256){
      int node = i >> 5, seg = i & 31;
      int nn = n0 + node;
      if (nn < N){
        float4 dv = *(const float4*)(OutSf + node * 132 + seg * 4);
        float4 hv = *(const float4*)(h + (size_t)nn * 128 + seg * 4);
        float4 ov = {hv.x + dv.x, hv.y + dv.y, hv.z + dv.z, hv.w + dv.w};
        *(float4*)(hout + (size_t)nn * 128 + seg * 4) = ov;
      }
    }
    __syncthreads();
  }
}

extern "C" void kernel_launch(void* const* d_in, const int* in_sizes, int n_in,
                              void* d_out, int out_size, void* d_ws, size_t ws_size,
                              hipStream_t stream)
{
  const float* h      = (const float*)d_in[0];
  const float* x      = (const float*)d_in[1];
  const int*   ei     = (const int*)  d_in[2];
  const float* ea     = (const float*)d_in[3];
  const float* t_emb  = (const float*)d_in[4];
  const float* We_w1  = (const float*)d_in[5];
  const float* We_b1  = (const float*)d_in[6];
  const float* We_w2  = (const float*)d_in[7];
  const float* We_b2  = (const float*)d_in[8];
  const float* Watt_w = (const float*)d_in[9];
  const float* Watt_b = (const float*)d_in[10];
  const float* Wx_w1  = (const float*)d_in[11];
  const float* Wx_b1  = (const float*)d_in[12];
  const float* Wx_w2  = (const float*)d_in[13];
  const float* Wx_b2  = (const float*)d_in[14];
  const float* Wx_w3  = (const float*)d_in[15];
  const float* Wh_w1  = (const float*)d_in[16];
  const float* Wh_b1  = (const float*)d_in[17];
  const float* Wh_w2  = (const float*)d_in[18];
  const float* Wh_b2  = (const float*)d_in[19];

  const int N = in_sizes[0] / HD;
  const int E = in_sizes[2] / 2;

  char* ws = (char*)d_ws;
  unsigned short* Aes  = (unsigned short*)ws;  ws += (size_t)N * HD * 2;
  unsigned short* Aed  = (unsigned short*)ws;  ws += (size_t)N * HD * 2;
  unsigned short* Axs  = (unsigned short*)ws;  ws += (size_t)N * HD * 2;
  unsigned short* Axd  = (unsigned short*)ws;  ws += (size_t)N * HD * 2;
  unsigned short* zpre = (unsigned short*)ws;  ws += (size_t)N * HD * 2;
  unsigned short* z2   = (unsigned short*)ws;  ws += (size_t)N * HD * 2;
  float* msg_agg = (float*)ws;                 ws += (size_t)N * HD * 4;

  float* hout = (float*)d_out;
  float* xout = hout + (size_t)N * HD;

  hipMemsetAsync(msg_agg, 0, (size_t)N * HD * 4, stream);
  hipMemcpyAsync(xout, x, (size_t)N * 3 * 4, hipMemcpyDeviceToDevice, stream);

  dim3 gP(192, 5);
  k_pre2<<<gP, 256, 0, stream>>>(h, t_emb, We_w1, We_b1, Wx_w1, Wx_b1,
                                 Wh_w1, Wh_b1, Aes, Aed, Axs, Axd, zpre, N);
  k_edge_msg<<<1536, 256, 0, stream>>>(ei, x, ea, Aes, Aed, We_w1, We_w2, We_b2,
                                       Watt_w, Watt_b, msg_agg, E);
  k_edge_coord<<<1536, 256, 0, stream>>>(ei, x, ea, Axs, Axd, Wx_w1, Wx_w2, Wx_b2,
                                         Wx_w3, xout, E);
  k_h1b2<<<512, 256, 0, stream>>>(msg_agg, zpre, Wh_w1, z2, N);
  k_h22<<<512, 256, 0, stream>>>(h, z2, Wh_w2, Wh_b2, hout, N);
}

// Round 6
// 582.601 us; speedup vs baseline: 1.1696x; 1.1696x over previous
//
#include <hip/hip_runtime.h>
#include <hip/hip_bf16.h>

#define HD 128
#define ED 16
#define TD 32

typedef __attribute__((ext_vector_type(8))) short short8;
typedef __attribute__((ext_vector_type(4))) float float4v;

__device__ __forceinline__ float siluf(float v){ return v * (1.0f / (1.0f + __expf(-v))); }

// bf16 pack/unpack helpers (RTNE)
__device__ __forceinline__ unsigned int bfbits(float x){
  unsigned int a = __float_as_uint(x);
  return (a + 0x7fffu + ((a >> 16) & 1u)) >> 16;
}
__device__ __forceinline__ unsigned int packbf(float lo, float hi){
  return (bfbits(lo) & 0xffffu) | (bfbits(hi) << 16);
}
__device__ __forceinline__ float unplo(unsigned int w){ return __uint_as_float(w << 16); }
__device__ __forceinline__ float unphi(unsigned int w){ return __uint_as_float(w & 0xffff0000u); }
__device__ __forceinline__ float b2f(unsigned short s){ return __uint_as_float(((unsigned int)s) << 16); }
__device__ __forceinline__ unsigned short f2b(float x){ return (unsigned short)bfbits(x); }

__device__ __forceinline__ void unp8(uint4 u, float* f){
  f[0]=unplo(u.x); f[1]=unphi(u.x); f[2]=unplo(u.y); f[3]=unphi(u.y);
  f[4]=unplo(u.z); f[5]=unphi(u.z); f[6]=unplo(u.w); f[7]=unphi(u.w);
}

__device__ __forceinline__ void atomAddF(float* p, float v){
  unsafeAtomicAdd(p, v);  // HW global_atomic_add_f32 on gfx950
}

// packed bf16 atomic add: one instruction adds 2 bf16 lanes-worth
__device__ __forceinline__ void atomAddBF2(unsigned short* p, unsigned int packed){
  asm volatile("global_atomic_pk_add_bf16 %0, %1, off"
               :: "v"((unsigned long long)(uintptr_t)p), "v"(packed) : "memory");
}

// ---------------------------------------------------------------------------
// Kernel 1: node-side first-layer GEMMs via MFMA (unchanged R4).
// ---------------------------------------------------------------------------
__global__ void __launch_bounds__(256) k_pre2(
    const float* __restrict__ h, const float* __restrict__ t_emb,
    const float* __restrict__ We_w1, const float* __restrict__ We_b1,
    const float* __restrict__ Wx_w1, const float* __restrict__ Wx_b1,
    const float* __restrict__ Wh_w1, const float* __restrict__ Wh_b1,
    unsigned short* __restrict__ Aes, unsigned short* __restrict__ Aed,
    unsigned short* __restrict__ Axs, unsigned short* __restrict__ Axd,
    unsigned short* __restrict__ zpre, int N)
{
  __shared__ unsigned short Wt[128 * 168];
  __shared__ unsigned short OutS[64 * 136];

  const int group = blockIdx.y;
  const float* Wsrc = (group <= 1) ? We_w1 : (group <= 3) ? Wx_w1 : Wh_w1;
  const float* bias = (group == 0) ? We_b1 : (group == 2) ? Wx_b1
                    : (group == 4) ? Wh_b1 : nullptr;
  unsigned short* out = (group == 0) ? Aes : (group == 1) ? Aed
                      : (group == 2) ? Axs : (group == 3) ? Axd : zpre;
  const int rowBase = (group == 1 || group == 3) ? 128 : 0;
  const int tBase   = (group == 0) ? 273 : (group == 2) ? 272 : -1;

  for (int i = threadIdx.x; i < 160 * 128; i += 256){
    int k = i >> 7, col = i & 127;
    float wv = 0.f;
    if (k < 128)      wv = Wsrc[(rowBase + k) * 128 + col];
    else if (tBase >= 0) wv = Wsrc[(tBase + (k - 128)) * 128 + col];
    Wt[col * 168 + k] = f2b(wv);
  }
  __syncthreads();

  const int lane = threadIdx.x & 63, w = threadIdx.x >> 6;
  const int m = lane & 15, q = lane >> 4;
  float bb[8];
  #pragma unroll
  for (int t = 0; t < 8; ++t) bb[t] = bias ? bias[t * 16 + m] : 0.f;

  const int ntiles = (N + 63) >> 6;
  for (int tile = blockIdx.x; tile < ntiles; tile += gridDim.x){
    const int n0 = tile << 6;
    const int n = min(n0 + w * 16 + m, N - 1);

    short8 a[5];
    #pragma unroll
    for (int step = 0; step < 4; ++step){
      float4 v0 = *(const float4*)(h + (size_t)n * 128 + step * 32 + q * 8);
      float4 v1 = *(const float4*)(h + (size_t)n * 128 + step * 32 + q * 8 + 4);
      union { short8 s; unsigned int u[4]; } av;
      av.u[0] = packbf(v0.x, v0.y); av.u[1] = packbf(v0.z, v0.w);
      av.u[2] = packbf(v1.x, v1.y); av.u[3] = packbf(v1.z, v1.w);
      a[step] = av.s;
    }
    {
      float4 v0 = *(const float4*)(t_emb + (size_t)n * 32 + q * 8);
      float4 v1 = *(const float4*)(t_emb + (size_t)n * 32 + q * 8 + 4);
      union { short8 s; unsigned int u[4]; } av;
      av.u[0] = packbf(v0.x, v0.y); av.u[1] = packbf(v0.z, v0.w);
      av.u[2] = packbf(v1.x, v1.y); av.u[3] = packbf(v1.z, v1.w);
      a[4] = av.s;
    }

    float4v acc[8];
    #pragma unroll
    for (int t = 0; t < 8; ++t) acc[t] = (float4v){0.f, 0.f, 0.f, 0.f};
    #pragma unroll
    for (int step = 0; step < 5; ++step){
      #pragma unroll
      for (int t = 0; t < 8; ++t){
        short8 b = *(const short8*)(Wt + (size_t)(t * 16 + m) * 168 + step * 32 + q * 8);
        acc[t] = __builtin_amdgcn_mfma_f32_16x16x32_bf16(a[step], b, acc[t], 0, 0, 0);
      }
    }

    #pragma unroll
    for (int t = 0; t < 8; ++t)
      #pragma unroll
      for (int r = 0; r < 4; ++r)
        OutS[(w * 16 + q * 4 + r) * 136 + t * 16 + m] = f2b(acc[t][r] + bb[t]);
    __syncthreads();
    for (int i = threadIdx.x; i < 64 * 16; i += 256){
      int node = i >> 4, seg = i & 15;
      int nn = n0 + node;
      if (nn < N)
        *(uint4*)(out + (size_t)nn * 128 + seg * 8) =
            *(const uint4*)(OutS + node * 136 + seg * 8);
    }
    __syncthreads();
  }
}

// ---------------------------------------------------------------------------
// Kernel 2: message path, wave-autonomous. One wave = one 16-edge tile.
// Aggregation via packed-bf16 HW atomics: ONE atomic instr per edge.
// ---------------------------------------------------------------------------
__global__ void __launch_bounds__(256, 3) k_edge_msg(
    const int* __restrict__ ei, const float* __restrict__ x,
    const float* __restrict__ ea,
    const unsigned short* __restrict__ Aes, const unsigned short* __restrict__ Aed,
    const float* __restrict__ We_w1, const float* __restrict__ We_w2,
    const float* __restrict__ We_b2, const float* __restrict__ Watt_w,
    const float* __restrict__ Watt_b,
    unsigned short* __restrict__ msg_agg, int E)
{
  __shared__ unsigned short W2t[128 * 136];    // 34816 B, [col][k]
  __shared__ unsigned short Ssh[4][16 * 136];  // per-wave: sums -> u -> m (bf16)
  __shared__ float          distS[4][16];
  __shared__ int            dsh[4][16];

  const int tid = threadIdx.x;
  for (int i = tid; i < 128 * 128; i += 256){
    int col = i & 127, k = i >> 7;
    W2t[col * 136 + k] = f2b(We_w2[k * 128 + col]);
  }
  __syncthreads();

  const int lane = tid & 63, w = tid >> 6;
  const int m = lane & 15, q = lane >> 4;

  // register B-frags for the ea|dist tail (rows 257..272 = ea, 256 = dist)
  short8 Bt[8];
  float web2[8], watt[8];
  #pragma unroll
  for (int t = 0; t < 8; ++t){
    const int col = t * 16 + m;
    web2[t] = We_b2[col];
    watt[t] = Watt_w[col];
    union { short8 v; unsigned short u[8]; } bt;
    #pragma unroll
    for (int j = 0; j < 8; ++j){
      int k = q * 8 + j;
      float wv = (k < 16) ? We_w1[(257 + k) * 128 + col]
               : (k == 16 ? We_w1[256 * 128 + col] : 0.f);
      bt.u[j] = f2b(wv);
    }
    Bt[t] = bt.v;
  }
  const float attb = Watt_b[0];

  unsigned short* S = Ssh[w];
  float* dS = distS[w];
  int*   dI = dsh[w];

  const int tiles = (E + 15) >> 4;
  const int wid = blockIdx.x * 4 + w;
  const int nwv = gridDim.x * 4;

  for (int tb = wid; tb < tiles; tb += nwv){
    const int e0 = tb << 4;

    // per-edge scalars (lanes 0..15)
    if (lane < 16){
      int eC = min(e0 + lane, E - 1);
      int s = ei[eC], d = ei[E + eC];
      float dx = x[s * 3 + 0] - x[d * 3 + 0];
      float dy = x[s * 3 + 1] - x[d * 3 + 1];
      float dz = x[s * 3 + 2] - x[d * 3 + 2];
      dS[lane] = dx * dx + dy * dy + dz * dz;
      dI[lane] = d;
    }

    // table-sum staging: 16 adjacent lanes cover one 256B row (proven pattern)
    #pragma unroll
    for (int it = 0; it < 4; ++it){
      const int eg = q + 4 * it;
      const int eC = min(e0 + eg, E - 1);
      const int s = ei[eC], d = ei[E + eC];
      uint4 gs = *(const uint4*)(Aes + (size_t)s * HD + m * 8);
      uint4 gd = *(const uint4*)(Aed + (size_t)d * HD + m * 8);
      float fa[8], fb[8];
      unp8(gs, fa); unp8(gd, fb);
      union { short8 v; unsigned int u[4]; } sv;
      #pragma unroll
      for (int jj = 0; jj < 4; ++jj)
        sv.u[jj] = packbf(fa[2 * jj] + fb[2 * jj], fa[2 * jj + 1] + fb[2 * jj + 1]);
      *(short8*)(S + eg * 136 + m * 8) = sv.v;
    }

    // tail A-frag in regs: k<16 = ea (consecutive rows -> coalesced), k==16 = dist
    union { short8 v; unsigned int u[4]; } at;
    at.u[0] = at.u[1] = at.u[2] = at.u[3] = 0u;
    {
      const int eC2 = min(e0 + m, E - 1);
      if (q < 2){
        float4 v0 = *(const float4*)(ea + (size_t)eC2 * ED + q * 8);
        float4 v1 = *(const float4*)(ea + (size_t)eC2 * ED + q * 8 + 4);
        at.u[0] = packbf(v0.x, v0.y); at.u[1] = packbf(v0.z, v0.w);
        at.u[2] = packbf(v1.x, v1.y); at.u[3] = packbf(v1.z, v1.w);
      } else if (q == 2){
        at.u[0] = bfbits(dS[m]) & 0xffffu;
      }
    }

    // tail MFMA with C initialized from staged sums; then silu -> u (bf16)
    #pragma unroll
    for (int t = 0; t < 8; ++t){
      float4v ci;
      #pragma unroll
      for (int r = 0; r < 4; ++r)
        ci[r] = b2f(S[(q * 4 + r) * 136 + t * 16 + m]);
      float4v o = __builtin_amdgcn_mfma_f32_16x16x32_bf16(at.v, Bt[t], ci, 0, 0, 0);
      #pragma unroll
      for (int r = 0; r < 4; ++r)
        S[(q * 4 + r) * 136 + t * 16 + m] = f2b(siluf(o[r]));
    }

    // layer-2 MFMA, B from shared W2t
    float4v c2[8];
    #pragma unroll
    for (int t = 0; t < 8; ++t) c2[t] = (float4v){0.f, 0.f, 0.f, 0.f};
    #pragma unroll
    for (int step = 0; step < 4; ++step){
      short8 a2 = *(const short8*)(S + m * 136 + step * 32 + q * 8);
      #pragma unroll
      for (int t = 0; t < 8; ++t){
        short8 b = *(const short8*)(W2t + (size_t)(t * 16 + m) * 136 + step * 32 + q * 8);
        c2[t] = __builtin_amdgcn_mfma_f32_16x16x32_bf16(a2, b, c2[t], 0, 0, 0);
      }
    }

    // attention + write gated m-values (bf16) back into S
    #pragma unroll
    for (int r = 0; r < 4; ++r){
      float mp[8], p = 0.f;
      #pragma unroll
      for (int t = 0; t < 8; ++t){
        mp[t] = c2[t][r] + web2[t];
        p = fmaf(mp[t], watt[t], p);
      }
      p += __shfl_xor(p, 1); p += __shfl_xor(p, 2);
      p += __shfl_xor(p, 4); p += __shfl_xor(p, 8);
      float att = 1.f / (1.f + __expf(-(p + attb)));
      #pragma unroll
      for (int t = 0; t < 8; ++t)
        S[(q * 4 + r) * 136 + t * 16 + m] = f2b(att * mp[t]);
    }

    // atomic scatter: ONE pk_add_bf16 instruction per edge (256B contiguous)
    #pragma unroll
    for (int eg = 0; eg < 16; ++eg){
      if (e0 + eg < E){
        unsigned int v = *(const unsigned int*)(S + eg * 136 + lane * 2);
        atomAddBF2(msg_agg + (size_t)dI[eg] * HD + lane * 2, v);
      }
    }
  }
}

// ---------------------------------------------------------------------------
// Kernel 3: coord path, wave-autonomous (unchanged R5).
// ---------------------------------------------------------------------------
__global__ void __launch_bounds__(256, 3) k_edge_coord(
    const int* __restrict__ ei, const float* __restrict__ x,
    const float* __restrict__ ea,
    const unsigned short* __restrict__ Axs, const unsigned short* __restrict__ Axd,
    const float* __restrict__ Wx_w1, const float* __restrict__ Wx_w2,
    const float* __restrict__ Wx_b2, const float* __restrict__ Wx_w3,
    float* __restrict__ xout, int E)
{
  __shared__ unsigned short W2t[128 * 136];    // 34816 B
  __shared__ unsigned short Ssh[4][16 * 136];
  __shared__ float          xaux[4][16 * 4];   // dx,dy,dz,rs per edge
  __shared__ int            dsh[4][16];

  const int tid = threadIdx.x;
  for (int i = tid; i < 128 * 128; i += 256){
    int col = i & 127, k = i >> 7;
    W2t[col * 136 + k] = f2b(Wx_w2[k * 128 + col]);
  }
  __syncthreads();

  const int lane = tid & 63, w = tid >> 6;
  const int m = lane & 15, q = lane >> 4;

  short8 Bt[8];
  float wxb2[8], w3v[8];
  #pragma unroll
  for (int t = 0; t < 8; ++t){
    const int col = t * 16 + m;
    wxb2[t] = Wx_b2[col];
    w3v[t]  = Wx_w3[col];
    union { short8 v; unsigned short u[8]; } bt;
    #pragma unroll
    for (int j = 0; j < 8; ++j){
      int k = q * 8 + j;
      bt.u[j] = f2b(k < 16 ? Wx_w1[(256 + k) * 128 + col] : 0.f);
    }
    Bt[t] = bt.v;
  }

  unsigned short* S = Ssh[w];
  float* xa = xaux[w];
  int*   dI = dsh[w];

  const int tiles = (E + 15) >> 4;
  const int wid = blockIdx.x * 4 + w;
  const int nwv = gridDim.x * 4;

  for (int tb = wid; tb < tiles; tb += nwv){
    const int e0 = tb << 4;

    if (lane < 16){
      int eC = min(e0 + lane, E - 1);
      int s = ei[eC], d = ei[E + eC];
      float dx = x[s * 3 + 0] - x[d * 3 + 0];
      float dy = x[s * 3 + 1] - x[d * 3 + 1];
      float dz = x[s * 3 + 2] - x[d * 3 + 2];
      float dist = dx * dx + dy * dy + dz * dz;
      xa[lane * 4 + 0] = dx;
      xa[lane * 4 + 1] = dy;
      xa[lane * 4 + 2] = dz;
      xa[lane * 4 + 3] = 2.5f / (sqrtf(dist + 1e-8f) + 1.0f);
      dI[lane] = d;
    }

    #pragma unroll
    for (int it = 0; it < 4; ++it){
      const int eg = q + 4 * it;
      const int eC = min(e0 + eg, E - 1);
      const int s = ei[eC], d = ei[E + eC];
      uint4 gs = *(const uint4*)(Axs + (size_t)s * HD + m * 8);
      uint4 gd = *(const uint4*)(Axd + (size_t)d * HD + m * 8);
      float fa[8], fb[8];
      unp8(gs, fa); unp8(gd, fb);
      union { short8 v; unsigned int u[4]; } sv;
      #pragma unroll
      for (int jj = 0; jj < 4; ++jj)
        sv.u[jj] = packbf(fa[2 * jj] + fb[2 * jj], fa[2 * jj + 1] + fb[2 * jj + 1]);
      *(short8*)(S + eg * 136 + m * 8) = sv.v;
    }

    union { short8 v; unsigned int u[4]; } at;
    at.u[0] = at.u[1] = at.u[2] = at.u[3] = 0u;
    if (q < 2){
      const int eC2 = min(e0 + m, E - 1);
      float4 v0 = *(const float4*)(ea + (size_t)eC2 * ED + q * 8);
      float4 v1 = *(const float4*)(ea + (size_t)eC2 * ED + q * 8 + 4);
      at.u[0] = packbf(v0.x, v0.y); at.u[1] = packbf(v0.z, v0.w);
      at.u[2] = packbf(v1.x, v1.y); at.u[3] = packbf(v1.z, v1.w);
    }

    #pragma unroll
    for (int t = 0; t < 8; ++t){
      float4v ci;
      #pragma unroll
      for (int r = 0; r < 4; ++r)
        ci[r] = b2f(S[(q * 4 + r) * 136 + t * 16 + m]);
      float4v o = __builtin_amdgcn_mfma_f32_16x16x32_bf16(at.v, Bt[t], ci, 0, 0, 0);
      #pragma unroll
      for (int r = 0; r < 4; ++r)
        S[(q * 4 + r) * 136 + t * 16 + m] = f2b(siluf(o[r]));
    }

    float4v c2[8];
    #pragma unroll
    for (int t = 0; t < 8; ++t) c2[t] = (float4v){0.f, 0.f, 0.f, 0.f};
    #pragma unroll
    for (int step = 0; step < 4; ++step){
      short8 a2 = *(const short8*)(S + m * 136 + step * 32 + q * 8);
      #pragma unroll
      for (int t = 0; t < 8; ++t){
        short8 b = *(const short8*)(W2t + (size_t)(t * 16 + m) * 136 + step * 32 + q * 8);
        c2[t] = __builtin_amdgcn_mfma_f32_16x16x32_bf16(a2, b, c2[t], 0, 0, 0);
      }
    }

    // coord weight + scatter (3 atomics per edge)
    #pragma unroll
    for (int r = 0; r < 4; ++r){
      float p = 0.f;
      #pragma unroll
      for (int t = 0; t < 8; ++t)
        p = fmaf(siluf(c2[t][r] + wxb2[t]), w3v[t], p);
      p += __shfl_xor(p, 1); p += __shfl_xor(p, 2);
      p += __shfl_xor(p, 4); p += __shfl_xor(p, 8);
      const int eg = q * 4 + r;
      float sc = tanhf(p) * xa[eg * 4 + 3];
      if (m < 3 && e0 + eg < E)
        atomAddF(xout + (size_t)dI[eg] * 3 + m, xa[eg * 4 + m] * sc);
    }
  }
}

// ---------------------------------------------------------------------------
// Kernel 4: z2 = bf16( silu( zpre + msg @ Wh_w1[128:256] ) ) — msg now bf16.
// ---------------------------------------------------------------------------
__global__ void __launch_bounds__(256) k_h1b2(
    const unsigned short* __restrict__ msg, const unsigned short* __restrict__ zpre,
    const float* __restrict__ Wh_w1, unsigned short* __restrict__ z2, int N)
{
  __shared__ unsigned short Wt[128 * 136];
  __shared__ unsigned short OutS[64 * 136];

  for (int i = threadIdx.x; i < 128 * 128; i += 256){
    int k = i >> 7, col = i & 127;
    Wt[col * 136 + k] = f2b(Wh_w1[(128 + k) * 128 + col]);
  }
  __syncthreads();

  const int lane = threadIdx.x & 63, w = threadIdx.x >> 6;
  const int m = lane & 15, q = lane >> 4;

  const int ntiles = (N + 63) >> 6;
  for (int tile = blockIdx.x; tile < ntiles; tile += gridDim.x){
    const int n0 = tile << 6;
    const int n = min(n0 + w * 16 + m, N - 1);

    short8 a[4];
    #pragma unroll
    for (int step = 0; step < 4; ++step)
      a[step] = *(const short8*)(msg + (size_t)n * 128 + step * 32 + q * 8);

    float4v acc[8];
    #pragma unroll
    for (int t = 0; t < 8; ++t) acc[t] = (float4v){0.f, 0.f, 0.f, 0.f};
    #pragma unroll
    for (int step = 0; step < 4; ++step){
      #pragma unroll
      for (int t = 0; t < 8; ++t){
        short8 b = *(const short8*)(Wt + (size_t)(t * 16 + m) * 136 + step * 32 + q * 8);
        acc[t] = __builtin_amdgcn_mfma_f32_16x16x32_bf16(a[step], b, acc[t], 0, 0, 0);
      }
    }

    #pragma unroll
    for (int t = 0; t < 8; ++t)
      #pragma unroll
      for (int r = 0; r < 4; ++r)
        OutS[(w * 16 + q * 4 + r) * 136 + t * 16 + m] = f2b(acc[t][r]);
    __syncthreads();
    for (int i = threadIdx.x; i < 64 * 16; i += 256){
      int node = i >> 4, seg = i & 15;
      int nn = n0 + node;
      if (nn < N){
        uint4 dv = *(const uint4*)(OutS + node * 136 + seg * 8);
        uint4 zv = *(const uint4*)(zpre + (size_t)nn * 128 + seg * 8);
        float fd[8], fz[8];
        unp8(dv, fd); unp8(zv, fz);
        uint4 ov;
        ov.x = packbf(siluf(fz[0] + fd[0]), siluf(fz[1] + fd[1]));
        ov.y = packbf(siluf(fz[2] + fd[2]), siluf(fz[3] + fd[3]));
        ov.z = packbf(siluf(fz[4] + fd[4]), siluf(fz[5] + fd[5]));
        ov.w = packbf(siluf(fz[6] + fd[6]), siluf(fz[7] + fd[7]));
        *(uint4*)(z2 + (size_t)nn * 128 + seg * 8) = ov;
      }
    }
    __syncthreads();
  }
}

// ---------------------------------------------------------------------------
// Kernel 5: hout = h + z2 @ Wh_w2 + Wh_b2  (unchanged R4)
// ---------------------------------------------------------------------------
__global__ void __launch_bounds__(256) k_h22(
    const float* __restrict__ h, const unsigned short* __restrict__ z2,
    const float* __restrict__ Wh_w2, const float* __restrict__ Wh_b2,
    float* __restrict__ hout, int N)
{
  __shared__ unsigned short Wt[128 * 136];
  __shared__ float OutSf[64 * 132];

  for (int i = threadIdx.x; i < 128 * 128; i += 256){
    int k = i >> 7, col = i & 127;
    Wt[col * 136 + k] = f2b(Wh_w2[k * 128 + col]);
  }
  __syncthreads();

  const int lane = threadIdx.x & 63, w = threadIdx.x >> 6;
  const int m = lane & 15, q = lane >> 4;
  float bb[8];
  #pragma unroll
  for (int t = 0; t < 8; ++t) bb[t] = Wh_b2[t * 16 + m];

  const int ntiles = (N + 63) >> 6;
  for (int tile = blockIdx.x; tile < ntiles; tile += gridDim.x){
    const int n0 = tile << 6;
    const int n = min(n0 + w * 16 + m, N - 1);

    short8 a[4];
    #pragma unroll
    for (int step = 0; step < 4; ++step)
      a[step] = *(const short8*)(z2 + (size_t)n * 128 + step * 32 + q * 8);

    float4v acc[8];
    #pragma unroll
    for (int t = 0; t < 8; ++t) acc[t] = (float4v){0.f, 0.f, 0.f, 0.f};
    #pragma unroll
    for (int step = 0; step < 4; ++step){
      #pragma unroll
      for (int t = 0; t < 8; ++t){
        short8 b = *(const short8*)(Wt + (size_t)(t * 16 + m) * 136 + step * 32 + q * 8);
        acc[t] = __builtin_amdgcn_mfma_f32_16x16x32_bf16(a[step], b, acc[t], 0, 0, 0);
      }
    }

    #pragma unroll
    for (int t = 0; t < 8; ++t)
      #pragma unroll
      for (int r = 0; r < 4; ++r)
        OutSf[(w * 16 + q * 4 + r) * 132 + t * 16 + m] = acc[t][r] + bb[t];
    __syncthreads();
    for (int i = threadIdx.x; i < 64 * 32; i += 256){
      int node = i >> 5, seg = i & 31;
      int nn = n0 + node;
      if (nn < N){
        float4 dv = *(const float4*)(OutSf + node * 132 + seg * 4);
        float4 hv = *(const float4*)(h + (size_t)nn * 128 + seg * 4);
        float4 ov = {hv.x + dv.x, hv.y + dv.y, hv.z + dv.z, hv.w + dv.w};
        *(float4*)(hout + (size_t)nn * 128 + seg * 4) = ov;
      }
    }
    __syncthreads();
  }
}

extern "C" void kernel_launch(void* const* d_in, const int* in_sizes, int n_in,
                              void* d_out, int out_size, void* d_ws, size_t ws_size,
                              hipStream_t stream)
{
  const float* h      = (const float*)d_in[0];
  const float* x      = (const float*)d_in[1];
  const int*   ei     = (const int*)  d_in[2];
  const float* ea     = (const float*)d_in[3];
  const float* t_emb  = (const float*)d_in[4];
  const float* We_w1  = (const float*)d_in[5];
  const float* We_b1  = (const float*)d_in[6];
  const float* We_w2  = (const float*)d_in[7];
  const float* We_b2  = (const float*)d_in[8];
  const float* Watt_w = (const float*)d_in[9];
  const float* Watt_b = (const float*)d_in[10];
  const float* Wx_w1  = (const float*)d_in[11];
  const float* Wx_b1  = (const float*)d_in[12];
  const float* Wx_w2  = (const float*)d_in[13];
  const float* Wx_b2  = (const float*)d_in[14];
  const float* Wx_w3  = (const float*)d_in[15];
  const float* Wh_w1  = (const float*)d_in[16];
  const float* Wh_b1  = (const float*)d_in[17];
  const float* Wh_w2  = (const float*)d_in[18];
  const float* Wh_b2  = (const float*)d_in[19];

  const int N = in_sizes[0] / HD;
  const int E = in_sizes[2] / 2;

  char* ws = (char*)d_ws;
  unsigned short* Aes  = (unsigned short*)ws;  ws += (size_t)N * HD * 2;
  unsigned short* Aed  = (unsigned short*)ws;  ws += (size_t)N * HD * 2;
  unsigned short* Axs  = (unsigned short*)ws;  ws += (size_t)N * HD * 2;
  unsigned short* Axd  = (unsigned short*)ws;  ws += (size_t)N * HD * 2;
  unsigned short* zpre = (unsigned short*)ws;  ws += (size_t)N * HD * 2;
  unsigned short* z2   = (unsigned short*)ws;  ws += (size_t)N * HD * 2;
  unsigned short* msg_agg = (unsigned short*)ws; ws += (size_t)N * HD * 2;

  float* hout = (float*)d_out;
  float* xout = hout + (size_t)N * HD;

  hipMemsetAsync(msg_agg, 0, (size_t)N * HD * 2, stream);
  hipMemcpyAsync(xout, x, (size_t)N * 3 * 4, hipMemcpyDeviceToDevice, stream);

  dim3 gP(192, 5);
  k_pre2<<<gP, 256, 0, stream>>>(h, t_emb, We_w1, We_b1, Wx_w1, Wx_b1,
                                 Wh_w1, Wh_b1, Aes, Aed, Axs, Axd, zpre, N);
  k_edge_msg<<<1536, 256, 0, stream>>>(ei, x, ea, Aes, Aed, We_w1, We_w2, We_b2,
                                       Watt_w, Watt_b, msg_agg, E);
  k_edge_coord<<<1536, 256, 0, stream>>>(ei, x, ea, Axs, Axd, Wx_w1, Wx_w2, Wx_b2,
                                         Wx_w3, xout, E);
  k_h1b2<<<512, 256, 0, stream>>>(msg_agg, zpre, Wh_w1, z2, N);
  k_h22<<<512, 256, 0, stream>>>(h, z2, Wh_w2, Wh_b2, hout, N);
}

// Round 7
// 576.250 us; speedup vs baseline: 1.1825x; 1.0110x over previous
//
#include <hip/hip_runtime.h>
#include <hip/hip_bf16.h>

#define HD 128
#define ED 16
#define TD 32

typedef __attribute__((ext_vector_type(8))) short short8;
typedef __attribute__((ext_vector_type(4))) float float4v;

__device__ __forceinline__ float siluf(float v){ return v * (1.0f / (1.0f + __expf(-v))); }

// bf16 pack/unpack helpers
__device__ __forceinline__ unsigned int bfbits(float x){          // RTNE
  unsigned int a = __float_as_uint(x);
  return (a + 0x7fffu + ((a >> 16) & 1u)) >> 16;
}
__device__ __forceinline__ unsigned int packbf(float lo, float hi){  // RTNE pair
  return (bfbits(lo) & 0xffffu) | (bfbits(hi) << 16);
}
// 1-op truncation pack via v_perm_b32: [lo.b2, lo.b3, hi.b2, hi.b3]
__device__ __forceinline__ unsigned int packtrunc(float lo, float hi){
  return __builtin_amdgcn_perm(__float_as_uint(hi), __float_as_uint(lo), 0x07060302u);
}
__device__ __forceinline__ unsigned short f2bt(float x){ return (unsigned short)(__float_as_uint(x) >> 16); }
__device__ __forceinline__ float unplo(unsigned int w){ return __uint_as_float(w << 16); }
__device__ __forceinline__ float unphi(unsigned int w){ return __uint_as_float(w & 0xffff0000u); }
__device__ __forceinline__ float b2f(unsigned short s){ return __uint_as_float(((unsigned int)s) << 16); }
__device__ __forceinline__ unsigned short f2b(float x){ return (unsigned short)bfbits(x); }

__device__ __forceinline__ void unp8(uint4 u, float* f){
  f[0]=unplo(u.x); f[1]=unphi(u.x); f[2]=unplo(u.y); f[3]=unphi(u.y);
  f[4]=unplo(u.z); f[5]=unphi(u.z); f[6]=unplo(u.w); f[7]=unphi(u.w);
}

__device__ __forceinline__ void atomAddF(float* p, float v){
  unsafeAtomicAdd(p, v);  // HW global_atomic_add_f32 on gfx950
}

// packed bf16 atomic add: one instruction adds 2 bf16 lanes-worth
__device__ __forceinline__ void atomAddBF2(unsigned short* p, unsigned int packed){
  asm volatile("global_atomic_pk_add_bf16 %0, %1, off"
               :: "v"((unsigned long long)(uintptr_t)p), "v"(packed) : "memory");
}

// ---------------------------------------------------------------------------
// Kernel 0: fp32 -> bf16 (RTNE) stream convert, 8 elems/thread-iter.
// ---------------------------------------------------------------------------
__global__ void __launch_bounds__(256) k_cvt(
    const float* __restrict__ src, unsigned short* __restrict__ dst, int n8)
{
  for (int i = blockIdx.x * 256 + threadIdx.x; i < n8; i += gridDim.x * 256){
    float4 v0 = *(const float4*)(src + (size_t)i * 8);
    float4 v1 = *(const float4*)(src + (size_t)i * 8 + 4);
    uint4 o;
    o.x = packbf(v0.x, v0.y); o.y = packbf(v0.z, v0.w);
    o.z = packbf(v1.x, v1.y); o.w = packbf(v1.z, v1.w);
    *(uint4*)(dst + (size_t)i * 8) = o;
  }
}

// ---------------------------------------------------------------------------
// Kernel 1: node-side first-layer GEMMs via MFMA; A from bf16 hb/tb.
// ---------------------------------------------------------------------------
__global__ void __launch_bounds__(256) k_pre2(
    const unsigned short* __restrict__ hb, const unsigned short* __restrict__ tb,
    const float* __restrict__ We_w1, const float* __restrict__ We_b1,
    const float* __restrict__ Wx_w1, const float* __restrict__ Wx_b1,
    const float* __restrict__ Wh_w1, const float* __restrict__ Wh_b1,
    unsigned short* __restrict__ Aes, unsigned short* __restrict__ Aed,
    unsigned short* __restrict__ Axs, unsigned short* __restrict__ Axd,
    unsigned short* __restrict__ zpre, int N)
{
  __shared__ unsigned short Wt[128 * 168];
  __shared__ unsigned short OutS[64 * 136];

  const int group = blockIdx.y;
  const float* Wsrc = (group <= 1) ? We_w1 : (group <= 3) ? Wx_w1 : Wh_w1;
  const float* bias = (group == 0) ? We_b1 : (group == 2) ? Wx_b1
                    : (group == 4) ? Wh_b1 : nullptr;
  unsigned short* out = (group == 0) ? Aes : (group == 1) ? Aed
                      : (group == 2) ? Axs : (group == 3) ? Axd : zpre;
  const int rowBase = (group == 1 || group == 3) ? 128 : 0;
  const int tBase   = (group == 0) ? 273 : (group == 2) ? 272 : -1;

  for (int i = threadIdx.x; i < 160 * 128; i += 256){
    int k = i >> 7, col = i & 127;
    float wv = 0.f;
    if (k < 128)      wv = Wsrc[(rowBase + k) * 128 + col];
    else if (tBase >= 0) wv = Wsrc[(tBase + (k - 128)) * 128 + col];
    Wt[col * 168 + k] = f2b(wv);
  }
  __syncthreads();

  const int lane = threadIdx.x & 63, w = threadIdx.x >> 6;
  const int m = lane & 15, q = lane >> 4;
  float bb[8];
  #pragma unroll
  for (int t = 0; t < 8; ++t) bb[t] = bias ? bias[t * 16 + m] : 0.f;

  const int ntiles = (N + 63) >> 6;
  for (int tile = blockIdx.x; tile < ntiles; tile += gridDim.x){
    const int n0 = tile << 6;
    const int n = min(n0 + w * 16 + m, N - 1);

    short8 a[5];
    #pragma unroll
    for (int step = 0; step < 4; ++step)
      a[step] = *(const short8*)(hb + (size_t)n * 128 + step * 32 + q * 8);
    a[4] = *(const short8*)(tb + (size_t)n * 32 + q * 8);

    float4v acc[8];
    #pragma unroll
    for (int t = 0; t < 8; ++t) acc[t] = (float4v){0.f, 0.f, 0.f, 0.f};
    #pragma unroll
    for (int step = 0; step < 5; ++step){
      #pragma unroll
      for (int t = 0; t < 8; ++t){
        short8 b = *(const short8*)(Wt + (size_t)(t * 16 + m) * 168 + step * 32 + q * 8);
        acc[t] = __builtin_amdgcn_mfma_f32_16x16x32_bf16(a[step], b, acc[t], 0, 0, 0);
      }
    }

    #pragma unroll
    for (int t = 0; t < 8; ++t)
      #pragma unroll
      for (int r = 0; r < 4; ++r)
        OutS[(w * 16 + q * 4 + r) * 136 + t * 16 + m] = f2b(acc[t][r] + bb[t]);
    __syncthreads();
    for (int i = threadIdx.x; i < 64 * 16; i += 256){
      int node = i >> 4, seg = i & 15;
      int nn = n0 + node;
      if (nn < N)
        *(uint4*)(out + (size_t)nn * 128 + seg * 8) =
            *(const uint4*)(OutS + node * 136 + seg * 8);
    }
    __syncthreads();
  }
}

// ---------------------------------------------------------------------------
// Kernel 2: message path, wave-autonomous, 512-thread blocks (8 waves).
// One wave = one 16-edge tile; packed-bf16 atomics (1 instr/edge).
// ---------------------------------------------------------------------------
__global__ void __launch_bounds__(512, 4) k_edge_msg(
    const int* __restrict__ ei, const float* __restrict__ x,
    const float* __restrict__ ea,
    const unsigned short* __restrict__ Aes, const unsigned short* __restrict__ Aed,
    const float* __restrict__ We_w1, const float* __restrict__ We_w2,
    const float* __restrict__ We_b2, const float* __restrict__ Watt_w,
    const float* __restrict__ Watt_b,
    unsigned short* __restrict__ msg_agg, int E)
{
  __shared__ unsigned short W2t[128 * 136];    // 34816 B, [col][k]
  __shared__ unsigned short Ssh[8][16 * 136];  // per-wave: sums -> u -> m (bf16)
  __shared__ float          distS[8][16];
  __shared__ int            dsh[8][16];

  const int tid = threadIdx.x;
  for (int i = tid; i < 128 * 128; i += 512){
    int col = i & 127, k = i >> 7;
    W2t[col * 136 + k] = f2b(We_w2[k * 128 + col]);
  }
  __syncthreads();

  const int lane = tid & 63, w = tid >> 6;
  const int m = lane & 15, q = lane >> 4;

  // register B-frags for the ea|dist tail (rows 257..272 = ea, 256 = dist)
  short8 Bt[8];
  float web2[8], watt[8];
  #pragma unroll
  for (int t = 0; t < 8; ++t){
    const int col = t * 16 + m;
    web2[t] = We_b2[col];
    watt[t] = Watt_w[col];
    union { short8 v; unsigned short u[8]; } bt;
    #pragma unroll
    for (int j = 0; j < 8; ++j){
      int k = q * 8 + j;
      float wv = (k < 16) ? We_w1[(257 + k) * 128 + col]
               : (k == 16 ? We_w1[256 * 128 + col] : 0.f);
      bt.u[j] = f2b(wv);
    }
    Bt[t] = bt.v;
  }
  const float attb = Watt_b[0];

  unsigned short* S = Ssh[w];
  float* dS = distS[w];
  int*   dI = dsh[w];

  const int tiles = (E + 15) >> 4;
  const int wid = blockIdx.x * 8 + w;
  const int nwv = gridDim.x * 8;

  for (int tb = wid; tb < tiles; tb += nwv){
    const int e0 = tb << 4;

    // per-edge scalars (lanes 0..15)
    if (lane < 16){
      int eC = min(e0 + lane, E - 1);
      int s = ei[eC], d = ei[E + eC];
      float dx = x[s * 3 + 0] - x[d * 3 + 0];
      float dy = x[s * 3 + 1] - x[d * 3 + 1];
      float dz = x[s * 3 + 2] - x[d * 3 + 2];
      dS[lane] = dx * dx + dy * dy + dz * dz;
      dI[lane] = d;
    }

    // table-sum staging: 16 adjacent lanes cover one 256B row
    #pragma unroll
    for (int it = 0; it < 4; ++it){
      const int eg = q + 4 * it;
      const int eC = min(e0 + eg, E - 1);
      const int s = ei[eC], d = ei[E + eC];
      uint4 gs = *(const uint4*)(Aes + (size_t)s * HD + m * 8);
      uint4 gd = *(const uint4*)(Aed + (size_t)d * HD + m * 8);
      float fa[8], fb[8];
      unp8(gs, fa); unp8(gd, fb);
      union { short8 v; unsigned int u[4]; } sv;
      #pragma unroll
      for (int jj = 0; jj < 4; ++jj)
        sv.u[jj] = packtrunc(fa[2 * jj] + fb[2 * jj], fa[2 * jj + 1] + fb[2 * jj + 1]);
      *(short8*)(S + eg * 136 + m * 8) = sv.v;
    }

    // tail A-frag in regs: k<16 = ea, k==16 = dist
    union { short8 v; unsigned int u[4]; } at;
    at.u[0] = at.u[1] = at.u[2] = at.u[3] = 0u;
    {
      const int eC2 = min(e0 + m, E - 1);
      if (q < 2){
        float4 v0 = *(const float4*)(ea + (size_t)eC2 * ED + q * 8);
        float4 v1 = *(const float4*)(ea + (size_t)eC2 * ED + q * 8 + 4);
        at.u[0] = packtrunc(v0.x, v0.y); at.u[1] = packtrunc(v0.z, v0.w);
        at.u[2] = packtrunc(v1.x, v1.y); at.u[3] = packtrunc(v1.z, v1.w);
      } else if (q == 2){
        at.u[0] = __float_as_uint(dS[m]) >> 16;
      }
    }

    // tail MFMA with C initialized from staged sums; then silu -> u (bf16)
    #pragma unroll
    for (int t = 0; t < 8; ++t){
      float4v ci;
      #pragma unroll
      for (int r = 0; r < 4; ++r)
        ci[r] = b2f(S[(q * 4 + r) * 136 + t * 16 + m]);
      float4v o = __builtin_amdgcn_mfma_f32_16x16x32_bf16(at.v, Bt[t], ci, 0, 0, 0);
      #pragma unroll
      for (int r = 0; r < 4; ++r)
        S[(q * 4 + r) * 136 + t * 16 + m] = f2bt(siluf(o[r]));
    }

    // layer-2 MFMA, B from shared W2t
    float4v c2[8];
    #pragma unroll
    for (int t = 0; t < 8; ++t) c2[t] = (float4v){0.f, 0.f, 0.f, 0.f};
    #pragma unroll
    for (int step = 0; step < 4; ++step){
      short8 a2 = *(const short8*)(S + m * 136 + step * 32 + q * 8);
      #pragma unroll
      for (int t = 0; t < 8; ++t){
        short8 b = *(const short8*)(W2t + (size_t)(t * 16 + m) * 136 + step * 32 + q * 8);
        c2[t] = __builtin_amdgcn_mfma_f32_16x16x32_bf16(a2, b, c2[t], 0, 0, 0);
      }
    }

    // attention + write gated m-values (bf16) back into S
    #pragma unroll
    for (int r = 0; r < 4; ++r){
      float mp[8], p = 0.f;
      #pragma unroll
      for (int t = 0; t < 8; ++t){
        mp[t] = c2[t][r] + web2[t];
        p = fmaf(mp[t], watt[t], p);
      }
      p += __shfl_xor(p, 1); p += __shfl_xor(p, 2);
      p += __shfl_xor(p, 4); p += __shfl_xor(p, 8);
      float att = 1.f / (1.f + __expf(-(p + attb)));
      #pragma unroll
      for (int t = 0; t < 8; ++t)
        S[(q * 4 + r) * 136 + t * 16 + m] = f2bt(att * mp[t]);
    }

    // atomic scatter: ONE pk_add_bf16 instruction per edge (256B contiguous)
    #pragma unroll
    for (int eg = 0; eg < 16; ++eg){
      if (e0 + eg < E){
        unsigned int v = *(const unsigned int*)(S + eg * 136 + lane * 2);
        atomAddBF2(msg_agg + (size_t)dI[eg] * HD + lane * 2, v);
      }
    }
  }
}

// ---------------------------------------------------------------------------
// Kernel 3: coord path, wave-autonomous, 512-thread blocks.
// ---------------------------------------------------------------------------
__global__ void __launch_bounds__(512, 4) k_edge_coord(
    const int* __restrict__ ei, const float* __restrict__ x,
    const float* __restrict__ ea,
    const unsigned short* __restrict__ Axs, const unsigned short* __restrict__ Axd,
    const float* __restrict__ Wx_w1, const float* __restrict__ Wx_w2,
    const float* __restrict__ Wx_b2, const float* __restrict__ Wx_w3,
    float* __restrict__ xout, int E)
{
  __shared__ unsigned short W2t[128 * 136];    // 34816 B
  __shared__ unsigned short Ssh[8][16 * 136];
  __shared__ float          xaux[8][16 * 4];   // dx,dy,dz,rs per edge
  __shared__ int            dsh[8][16];

  const int tid = threadIdx.x;
  for (int i = tid; i < 128 * 128; i += 512){
    int col = i & 127, k = i >> 7;
    W2t[col * 136 + k] = f2b(Wx_w2[k * 128 + col]);
  }
  __syncthreads();

  const int lane = tid & 63, w = tid >> 6;
  const int m = lane & 15, q = lane >> 4;

  short8 Bt[8];
  float wxb2[8], w3v[8];
  #pragma unroll
  for (int t = 0; t < 8; ++t){
    const int col = t * 16 + m;
    wxb2[t] = Wx_b2[col];
    w3v[t]  = Wx_w3[col];
    union { short8 v; unsigned short u[8]; } bt;
    #pragma unroll
    for (int j = 0; j < 8; ++j){
      int k = q * 8 + j;
      bt.u[j] = f2b(k < 16 ? Wx_w1[(256 + k) * 128 + col] : 0.f);
    }
    Bt[t] = bt.v;
  }

  unsigned short* S = Ssh[w];
  float* xa = xaux[w];
  int*   dI = dsh[w];

  const int tiles = (E + 15) >> 4;
  const int wid = blockIdx.x * 8 + w;
  const int nwv = gridDim.x * 8;

  for (int tb = wid; tb < tiles; tb += nwv){
    const int e0 = tb << 4;

    if (lane < 16){
      int eC = min(e0 + lane, E - 1);
      int s = ei[eC], d = ei[E + eC];
      float dx = x[s * 3 + 0] - x[d * 3 + 0];
      float dy = x[s * 3 + 1] - x[d * 3 + 1];
      float dz = x[s * 3 + 2] - x[d * 3 + 2];
      float dist = dx * dx + dy * dy + dz * dz;
      xa[lane * 4 + 0] = dx;
      xa[lane * 4 + 1] = dy;
      xa[lane * 4 + 2] = dz;
      xa[lane * 4 + 3] = 2.5f / (sqrtf(dist + 1e-8f) + 1.0f);
      dI[lane] = d;
    }

    #pragma unroll
    for (int it = 0; it < 4; ++it){
      const int eg = q + 4 * it;
      const int eC = min(e0 + eg, E - 1);
      const int s = ei[eC], d = ei[E + eC];
      uint4 gs = *(const uint4*)(Axs + (size_t)s * HD + m * 8);
      uint4 gd = *(const uint4*)(Axd + (size_t)d * HD + m * 8);
      float fa[8], fb[8];
      unp8(gs, fa); unp8(gd, fb);
      union { short8 v; unsigned int u[4]; } sv;
      #pragma unroll
      for (int jj = 0; jj < 4; ++jj)
        sv.u[jj] = packtrunc(fa[2 * jj] + fb[2 * jj], fa[2 * jj + 1] + fb[2 * jj + 1]);
      *(short8*)(S + eg * 136 + m * 8) = sv.v;
    }

    union { short8 v; unsigned int u[4]; } at;
    at.u[0] = at.u[1] = at.u[2] = at.u[3] = 0u;
    if (q < 2){
      const int eC2 = min(e0 + m, E - 1);
      float4 v0 = *(const float4*)(ea + (size_t)eC2 * ED + q * 8);
      float4 v1 = *(const float4*)(ea + (size_t)eC2 * ED + q * 8 + 4);
      at.u[0] = packtrunc(v0.x, v0.y); at.u[1] = packtrunc(v0.z, v0.w);
      at.u[2] = packtrunc(v1.x, v1.y); at.u[3] = packtrunc(v1.z, v1.w);
    }

    #pragma unroll
    for (int t = 0; t < 8; ++t){
      float4v ci;
      #pragma unroll
      for (int r = 0; r < 4; ++r)
        ci[r] = b2f(S[(q * 4 + r) * 136 + t * 16 + m]);
      float4v o = __builtin_amdgcn_mfma_f32_16x16x32_bf16(at.v, Bt[t], ci, 0, 0, 0);
      #pragma unroll
      for (int r = 0; r < 4; ++r)
        S[(q * 4 + r) * 136 + t * 16 + m] = f2bt(siluf(o[r]));
    }

    float4v c2[8];
    #pragma unroll
    for (int t = 0; t < 8; ++t) c2[t] = (float4v){0.f, 0.f, 0.f, 0.f};
    #pragma unroll
    for (int step = 0; step < 4; ++step){
      short8 a2 = *(const short8*)(S + m * 136 + step * 32 + q * 8);
      #pragma unroll
      for (int t = 0; t < 8; ++t){
        short8 b = *(const short8*)(W2t + (size_t)(t * 16 + m) * 136 + step * 32 + q * 8);
        c2[t] = __builtin_amdgcn_mfma_f32_16x16x32_bf16(a2, b, c2[t], 0, 0, 0);
      }
    }

    // coord weight + scatter (3 atomics per edge)
    #pragma unroll
    for (int r = 0; r < 4; ++r){
      float p = 0.f;
      #pragma unroll
      for (int t = 0; t < 8; ++t)
        p = fmaf(siluf(c2[t][r] + wxb2[t]), w3v[t], p);
      p += __shfl_xor(p, 1); p += __shfl_xor(p, 2);
      p += __shfl_xor(p, 4); p += __shfl_xor(p, 8);
      const int eg = q * 4 + r;
      float sc = tanhf(p) * xa[eg * 4 + 3];
      if (m < 3 && e0 + eg < E)
        atomAddF(xout + (size_t)dI[eg] * 3 + m, xa[eg * 4 + m] * sc);
    }
  }
}

// ---------------------------------------------------------------------------
// Kernel 4: z2 = bf16( silu( zpre + msg @ Wh_w1[128:256] ) ) — msg bf16.
// ---------------------------------------------------------------------------
__global__ void __launch_bounds__(256) k_h1b2(
    const unsigned short* __restrict__ msg, const unsigned short* __restrict__ zpre,
    const float* __restrict__ Wh_w1, unsigned short* __restrict__ z2, int N)
{
  __shared__ unsigned short Wt[128 * 136];
  __shared__ unsigned short OutS[64 * 136];

  for (int i = threadIdx.x; i < 128 * 128; i += 256){
    int k = i >> 7, col = i & 127;
    Wt[col * 136 + k] = f2b(Wh_w1[(128 + k) * 128 + col]);
  }
  __syncthreads();

  const int lane = threadIdx.x & 63, w = threadIdx.x >> 6;
  const int m = lane & 15, q = lane >> 4;

  const int ntiles = (N + 63) >> 6;
  for (int tile = blockIdx.x; tile < ntiles; tile += gridDim.x){
    const int n0 = tile << 6;
    const int n = min(n0 + w * 16 + m, N - 1);

    short8 a[4];
    #pragma unroll
    for (int step = 0; step < 4; ++step)
      a[step] = *(const short8*)(msg + (size_t)n * 128 + step * 32 + q * 8);

    float4v acc[8];
    #pragma unroll
    for (int t = 0; t < 8; ++t) acc[t] = (float4v){0.f, 0.f, 0.f, 0.f};
    #pragma unroll
    for (int step = 0; step < 4; ++step){
      #pragma unroll
      for (int t = 0; t < 8; ++t){
        short8 b = *(const short8*)(Wt + (size_t)(t * 16 + m) * 136 + step * 32 + q * 8);
        acc[t] = __builtin_amdgcn_mfma_f32_16x16x32_bf16(a[step], b, acc[t], 0, 0, 0);
      }
    }

    #pragma unroll
    for (int t = 0; t < 8; ++t)
      #pragma unroll
      for (int r = 0; r < 4; ++r)
        OutS[(w * 16 + q * 4 + r) * 136 + t * 16 + m] = f2b(acc[t][r]);
    __syncthreads();
    for (int i = threadIdx.x; i < 64 * 16; i += 256){
      int node = i >> 4, seg = i & 15;
      int nn = n0 + node;
      if (nn < N){
        uint4 dv = *(const uint4*)(OutS + node * 136 + seg * 8);
        uint4 zv = *(const uint4*)(zpre + (size_t)nn * 128 + seg * 8);
        float fd[8], fz[8];
        unp8(dv, fd); unp8(zv, fz);
        uint4 ov;
        ov.x = packbf(siluf(fz[0] + fd[0]), siluf(fz[1] + fd[1]));
        ov.y = packbf(siluf(fz[2] + fd[2]), siluf(fz[3] + fd[3]));
        ov.z = packbf(siluf(fz[4] + fd[4]), siluf(fz[5] + fd[5]));
        ov.w = packbf(siluf(fz[6] + fd[6]), siluf(fz[7] + fd[7]));
        *(uint4*)(z2 + (size_t)nn * 128 + seg * 8) = ov;
      }
    }
    __syncthreads();
  }
}

// ---------------------------------------------------------------------------
// Kernel 5: hout = h + z2 @ Wh_w2 + Wh_b2
// ---------------------------------------------------------------------------
__global__ void __launch_bounds__(256) k_h22(
    const float* __restrict__ h, const unsigned short* __restrict__ z2,
    const float* __restrict__ Wh_w2, const float* __restrict__ Wh_b2,
    float* __restrict__ hout, int N)
{
  __shared__ unsigned short Wt[128 * 136];
  __shared__ float OutSf[64 * 132];

  for (int i = threadIdx.x; i < 128 * 128; i += 256){
    int k = i >> 7, col = i & 127;
    Wt[col * 136 + k] = f2b(Wh_w2[k * 128 + col]);
  }
  __syncthreads();

  const int lane = threadIdx.x & 63, w = threadIdx.x >> 6;
  const int m = lane & 15, q = lane >> 4;
  float bb[8];
  #pragma unroll
  for (int t = 0; t < 8; ++t) bb[t] = Wh_b2[t * 16 + m];

  const int ntiles = (N + 63) >> 6;
  for (int tile = blockIdx.x; tile < ntiles; tile += gridDim.x){
    const int n0 = tile << 6;
    const int n = min(n0 + w * 16 + m, N - 1);

    short8 a[4];
    #pragma unroll
    for (int step = 0; step < 4; ++step)
      a[step] = *(const short8*)(z2 + (size_t)n * 128 + step * 32 + q * 8);

    float4v acc[8];
    #pragma unroll
    for (int t = 0; t < 8; ++t) acc[t] = (float4v){0.f, 0.f, 0.f, 0.f};
    #pragma unroll
    for (int step = 0; step < 4; ++step){
      #pragma unroll
      for (int t = 0; t < 8; ++t){
        short8 b = *(const short8*)(Wt + (size_t)(t * 16 + m) * 136 + step * 32 + q * 8);
        acc[t] = __builtin_amdgcn_mfma_f32_16x16x32_bf16(a[step], b, acc[t], 0, 0, 0);
      }
    }

    #pragma unroll
    for (int t = 0; t < 8; ++t)
      #pragma unroll
      for (int r = 0; r < 4; ++r)
        OutSf[(w * 16 + q * 4 + r) * 132 + t * 16 + m] = acc[t][r] + bb[t];
    __syncthreads();
    for (int i = threadIdx.x; i < 64 * 32; i += 256){
      int node = i >> 5, seg = i & 31;
      int nn = n0 + node;
      if (nn < N){
        float4 dv = *(const float4*)(OutSf + node * 132 + seg * 4);
        float4 hv = *(const float4*)(h + (size_t)nn * 128 + seg * 4);
        float4 ov = {hv.x + dv.x, hv.y + dv.y, hv.z + dv.z, hv.w + dv.w};
        *(float4*)(hout + (size_t)nn * 128 + seg * 4) = ov;
      }
    }
    __syncthreads();
  }
}

extern "C" void kernel_launch(void* const* d_in, const int* in_sizes, int n_in,
                              void* d_out, int out_size, void* d_ws, size_t ws_size,
                              hipStream_t stream)
{
  const float* h      = (const float*)d_in[0];
  const float* x      = (const float*)d_in[1];
  const int*   ei     = (const int*)  d_in[2];
  const float* ea     = (const float*)d_in[3];
  const float* t_emb  = (const float*)d_in[4];
  const float* We_w1  = (const float*)d_in[5];
  const float* We_b1  = (const float*)d_in[6];
  const float* We_w2  = (const float*)d_in[7];
  const float* We_b2  = (const float*)d_in[8];
  const float* Watt_w = (const float*)d_in[9];
  const float* Watt_b = (const float*)d_in[10];
  const float* Wx_w1  = (const float*)d_in[11];
  const float* Wx_b1  = (const float*)d_in[12];
  const float* Wx_w2  = (const float*)d_in[13];
  const float* Wx_b2  = (const float*)d_in[14];
  const float* Wx_w3  = (const float*)d_in[15];
  const float* Wh_w1  = (const float*)d_in[16];
  const float* Wh_b1  = (const float*)d_in[17];
  const float* Wh_w2  = (const float*)d_in[18];
  const float* Wh_b2  = (const float*)d_in[19];

  const int N = in_sizes[0] / HD;
  const int E = in_sizes[2] / 2;

  char* ws = (char*)d_ws;
  unsigned short* Aes  = (unsigned short*)ws;  ws += (size_t)N * HD * 2;
  unsigned short* Aed  = (unsigned short*)ws;  ws += (size_t)N * HD * 2;
  unsigned short* Axs  = (unsigned short*)ws;  ws += (size_t)N * HD * 2;
  unsigned short* Axd  = (unsigned short*)ws;  ws += (size_t)N * HD * 2;
  unsigned short* zpre = (unsigned short*)ws;  ws += (size_t)N * HD * 2;
  unsigned short* z2   = (unsigned short*)ws;  ws += (size_t)N * HD * 2;
  unsigned short* msg_agg = (unsigned short*)ws; ws += (size_t)N * HD * 2;
  unsigned short* hb   = (unsigned short*)ws;  ws += (size_t)N * HD * 2;
  unsigned short* tb   = (unsigned short*)ws;  ws += (size_t)N * TD * 2;

  float* hout = (float*)d_out;
  float* xout = hout + (size_t)N * HD;

  hipMemsetAsync(msg_agg, 0, (size_t)N * HD * 2, stream);
  hipMemcpyAsync(xout, x, (size_t)N * 3 * 4, hipMemcpyDeviceToDevice, stream);

  k_cvt<<<400, 256, 0, stream>>>(h, hb, N * (HD / 8));
  k_cvt<<<100, 256, 0, stream>>>(t_emb, tb, N * (TD / 8));

  dim3 gP(192, 5);
  k_pre2<<<gP, 256, 0, stream>>>(hb, tb, We_w1, We_b1, Wx_w1, Wx_b1,
                                 Wh_w1, Wh_b1, Aes, Aed, Axs, Axd, zpre, N);
  k_edge_msg<<<512, 512, 0, stream>>>(ei, x, ea, Aes, Aed, We_w1, We_w2, We_b2,
                                      Watt_w, Watt_b, msg_agg, E);
  k_edge_coord<<<512, 512, 0, stream>>>(ei, x, ea, Axs, Axd, Wx_w1, Wx_w2, Wx_b2,
                                        Wx_w3, xout, E);
  k_h1b2<<<512, 256, 0, stream>>>(msg_agg, zpre, Wh_w1, z2, N);
  k_h22<<<512, 256, 0, stream>>>(h, z2, Wh_w2, Wh_b2, hout, N);
}